// Round 2
// baseline (1298.538 us; speedup 1.0000x reference)
//
#include <hip/hip_runtime.h>
#include <hip/hip_bf16.h>

#define NB   8
#define CIN  256
#define NN   4096
#define DK   64
#define DOUT 256

typedef float f32x4 __attribute__((ext_vector_type(4)));
typedef short short8 __attribute__((ext_vector_type(8)));

__device__ __forceinline__ short f2bf(float f) {
    unsigned u = __builtin_bit_cast(unsigned, f);
    u = (u + 0x7FFFu + ((u >> 16) & 1u)) >> 16;   // RNE
    return (short)u;
}

// ---------------------------------------------------------------------------
// Projection: q = x^T Wq^T / 8 (bf16, row-major NxDK)
//             k = x^T Wk^T     (bf16, row-major NxDK)
//             vt = Wv x        (bf16, DOUT x N  -- transposed for attn B-frags)
// grid (NN/64, 6, NB), block 256. jt: 0=Q, 1=K, 2..5=V rows (jt-2)*64.
// ---------------------------------------------------------------------------
__global__ __launch_bounds__(256) void proj_kernel(
    const float* __restrict__ x,  const float* __restrict__ Wq,
    const float* __restrict__ Wk, const float* __restrict__ Wv,
    short* __restrict__ Qw, short* __restrict__ Kw, short* __restrict__ Vw)
{
    __shared__ float Wlds[CIN][64];
    const int t  = threadIdx.x;
    const int nt = blockIdx.x;
    const int jt = blockIdx.y;
    const int b  = blockIdx.z;

    const float* Wsrc; int jrow0;
    if (jt == 0)      { Wsrc = Wq; jrow0 = 0; }
    else if (jt == 1) { Wsrc = Wk; jrow0 = 0; }
    else              { Wsrc = Wv; jrow0 = (jt - 2) * 64; }

    // stage W tile (64 j-rows x 256 c) into LDS transposed: Wlds[c][j]
    {
        const int jj = t & 63, chunk = t >> 6;
        const float* src = Wsrc + (size_t)(jrow0 + jj) * CIN + chunk * 64;
        #pragma unroll
        for (int i = 0; i < 64; ++i)
            Wlds[chunk * 64 + i][jj] = src[i];
    }
    __syncthreads();

    const int n  = nt * 64 + (t & 63);
    const int jg = t >> 6;                 // 0..3 -> 16 j's each
    const float* xb = x + (size_t)b * CIN * NN + n;

    float acc[16];
    #pragma unroll
    for (int i = 0; i < 16; ++i) acc[i] = 0.f;

    for (int c = 0; c < CIN; ++c) {
        float xv = xb[(size_t)c * NN];
        #pragma unroll
        for (int i = 0; i < 16; ++i)
            acc[i] = fmaf(xv, Wlds[c][jg * 16 + i], acc[i]);
    }

    if (jt < 2) {
        short* dst = (jt == 0 ? Qw : Kw)
                   + (size_t)b * NN * DK + (size_t)n * DK + jg * 16;
        const float s = (jt == 0) ? 0.125f : 1.0f;   // fold 1/sqrt(64) into Q
        #pragma unroll
        for (int i = 0; i < 16; ++i) dst[i] = f2bf(acc[i] * s);
    } else {
        const int o0 = (jt - 2) * 64 + jg * 16;
        short* dst = Vw + (size_t)b * DOUT * NN + n;
        #pragma unroll
        for (int i = 0; i < 16; ++i) dst[(size_t)(o0 + i) * NN] = f2bf(acc[i]);
    }
}

// ---------------------------------------------------------------------------
// Flash attention: per block 64 q-rows, 4 waves x 16 rows, KVBLK=64.
// S via mfma_f32_16x16x32_bf16 (A=Q rows, B=K^T), online softmax in D layout
// (row=(lane>>4)*4+reg, col=lane&15), P through per-wave LDS, PV MFMA,
// epilogue writes out[b][o][n] fp32.
// grid (NN/64, NB), block 256.
// ---------------------------------------------------------------------------
__global__ __launch_bounds__(256) void attn_kernel(
    const short* __restrict__ Q, const short* __restrict__ K,
    const short* __restrict__ Vt, float* __restrict__ out)
{
    __shared__ short P_lds[4][16][64];
    const int b  = blockIdx.y;
    const int q0 = blockIdx.x * 64;
    const int w  = threadIdx.x >> 6;
    const int l  = threadIdx.x & 63;
    const int hi = l >> 4, lo = l & 15;

    const short* Qb = Q  + (size_t)b * NN * DK;
    const short* Kb = K  + (size_t)b * NN * DK;
    const short* Vb = Vt + (size_t)b * DOUT * NN;

    // Q A-fragments: lane -> row = lane&15, k = (lane>>4)*8 + j (+32 per step)
    const int qrow = q0 + w * 16 + lo;
    const short8 aq0 = *(const short8*)(Qb + (size_t)qrow * DK + hi * 8);
    const short8 aq1 = *(const short8*)(Qb + (size_t)qrow * DK + hi * 8 + 32);

    f32x4 oacc[16];
    #pragma unroll
    for (int i = 0; i < 16; ++i) oacc[i] = f32x4{0.f, 0.f, 0.f, 0.f};
    float mrun[4], lrun[4];
    #pragma unroll
    for (int r = 0; r < 4; ++r) { mrun[r] = -1e30f; lrun[r] = 0.f; }

    for (int m0 = 0; m0 < NN; m0 += 64) {
        // ---- S = Q K^T (rows: this wave's 16 q-rows; cols: 64 m) ----
        f32x4 s[4];
        #pragma unroll
        for (int mt = 0; mt < 4; ++mt) {
            const short* kr = Kb + (size_t)(m0 + mt * 16 + lo) * DK + hi * 8;
            short8 bk0 = *(const short8*)(kr);
            short8 bk1 = *(const short8*)(kr + 32);
            f32x4 acc = {0.f, 0.f, 0.f, 0.f};
            acc = __builtin_amdgcn_mfma_f32_16x16x32_bf16(aq0, bk0, acc, 0, 0, 0);
            acc = __builtin_amdgcn_mfma_f32_16x16x32_bf16(aq1, bk1, acc, 0, 0, 0);
            s[mt] = acc;
        }
        // ---- online softmax (row r lives on the 16 lanes of group hi) ----
        float rmax[4], rsum[4], alpha[4];
        #pragma unroll
        for (int r = 0; r < 4; ++r)
            rmax[r] = fmaxf(fmaxf(s[0][r], s[1][r]), fmaxf(s[2][r], s[3][r]));
        #pragma unroll
        for (int d = 1; d < 16; d <<= 1) {
            #pragma unroll
            for (int r = 0; r < 4; ++r)
                rmax[r] = fmaxf(rmax[r], __shfl_xor(rmax[r], d, 64));
        }
        #pragma unroll
        for (int r = 0; r < 4; ++r) {
            float mn = fmaxf(mrun[r], rmax[r]);
            alpha[r] = __expf(mrun[r] - mn);
            mrun[r] = mn;
            rsum[r] = 0.f;
        }
        #pragma unroll
        for (int mt = 0; mt < 4; ++mt) {
            #pragma unroll
            for (int r = 0; r < 4; ++r) {
                float p = __expf(s[mt][r] - mrun[r]);
                s[mt][r] = p;
                rsum[r] += p;
            }
        }
        #pragma unroll
        for (int d = 1; d < 16; d <<= 1) {
            #pragma unroll
            for (int r = 0; r < 4; ++r)
                rsum[r] += __shfl_xor(rsum[r], d, 64);
        }
        bool resc = false;
        #pragma unroll
        for (int r = 0; r < 4; ++r) {
            lrun[r] = lrun[r] * alpha[r] + rsum[r];
            resc |= (alpha[r] != 1.f);
        }
        if (__any(resc)) {
            #pragma unroll
            for (int i = 0; i < 16; ++i) {
                #pragma unroll
                for (int r = 0; r < 4; ++r) oacc[i][r] *= alpha[r];
            }
        }
        // ---- P -> LDS (per-wave region), re-read as A-fragment ----
        #pragma unroll
        for (int mt = 0; mt < 4; ++mt) {
            #pragma unroll
            for (int r = 0; r < 4; ++r)
                P_lds[w][hi * 4 + r][mt * 16 + lo] = f2bf(s[mt][r]);
        }
        asm volatile("s_waitcnt lgkmcnt(0)" ::: "memory");
        __builtin_amdgcn_sched_barrier(0);
        short8 pa0 = *(const short8*)(&P_lds[w][lo][hi * 8]);
        short8 pa1 = *(const short8*)(&P_lds[w][lo][hi * 8 + 32]);
        // ---- O += P V ----
        #pragma unroll 4
        for (int ot = 0; ot < 16; ++ot) {
            const short* vr = Vb + (size_t)(ot * 16 + lo) * NN + m0 + hi * 8;
            short8 bv0 = *(const short8*)(vr);
            short8 bv1 = *(const short8*)(vr + 32);
            oacc[ot] = __builtin_amdgcn_mfma_f32_16x16x32_bf16(pa0, bv0, oacc[ot], 0, 0, 0);
            oacc[ot] = __builtin_amdgcn_mfma_f32_16x16x32_bf16(pa1, bv1, oacc[ot], 0, 0, 0);
        }
    }
    // ---- epilogue: out[b][o][n] = oacc / l ----
    float inv[4];
    #pragma unroll
    for (int r = 0; r < 4; ++r) inv[r] = 1.f / lrun[r];
    float* ob = out + (size_t)b * DOUT * NN;
    #pragma unroll
    for (int ot = 0; ot < 16; ++ot) {
        #pragma unroll
        for (int r = 0; r < 4; ++r)
            ob[(size_t)(ot * 16 + lo) * NN + (q0 + w * 16 + hi * 4 + r)]
                = oacc[ot][r] * inv[r];
    }
}

// ---------------------------------------------------------------------------
extern "C" void kernel_launch(void* const* d_in, const int* in_sizes, int n_in,
                              void* d_out, int out_size, void* d_ws, size_t ws_size,
                              hipStream_t stream)
{
    const float* x  = (const float*)d_in[0];
    const float* Wq = (const float*)d_in[1];
    const float* Wk = (const float*)d_in[2];
    const float* Wv = (const float*)d_in[3];
    float* out = (float*)d_out;

    short* Qw = (short*)d_ws;                       // B*N*DK bf16  (4 MB)
    short* Kw = Qw + (size_t)NB * NN * DK;          // B*N*DK bf16  (4 MB)
    short* Vw = Kw + (size_t)NB * NN * DK;          // B*DOUT*N bf16 (16 MB)

    proj_kernel<<<dim3(NN / 64, 6, NB), 256, 0, stream>>>(x, Wq, Wk, Wv, Qw, Kw, Vw);
    attn_kernel<<<dim3(NN / 64, NB), 256, 0, stream>>>(Qw, Kw, Vw, out);
}

// Round 3
// 788.546 us; speedup vs baseline: 1.6467x; 1.6467x over previous
//
#include <hip/hip_runtime.h>
#include <hip/hip_bf16.h>

#define NB   8
#define CIN  256
#define NN   4096
#define DK   64
#define DOUT 256

typedef float f32x4 __attribute__((ext_vector_type(4)));
typedef short short8 __attribute__((ext_vector_type(8)));

__device__ __forceinline__ short f2bf(float f) {
    unsigned u = __builtin_bit_cast(unsigned, f);
    u = (u + 0x7FFFu + ((u >> 16) & 1u)) >> 16;   // RNE
    return (short)u;
}

// ---------------------------------------------------------------------------
// Projection: q = x^T Wq^T / 8 (bf16, row-major NxDK)
//             k = x^T Wk^T     (bf16, row-major NxDK)
//             vt = Wv x        (bf16, DOUT x N  -- transposed for attn B-frags)
// grid (NN/64, 6, NB), block 256. jt: 0=Q, 1=K, 2..5=V rows (jt-2)*64.
// ---------------------------------------------------------------------------
__global__ __launch_bounds__(256) void proj_kernel(
    const float* __restrict__ x,  const float* __restrict__ Wq,
    const float* __restrict__ Wk, const float* __restrict__ Wv,
    short* __restrict__ Qw, short* __restrict__ Kw, short* __restrict__ Vw)
{
    __shared__ float Wlds[CIN][64];
    const int t  = threadIdx.x;
    const int nt = blockIdx.x;
    const int jt = blockIdx.y;
    const int b  = blockIdx.z;

    const float* Wsrc; int jrow0;
    if (jt == 0)      { Wsrc = Wq; jrow0 = 0; }
    else if (jt == 1) { Wsrc = Wk; jrow0 = 0; }
    else              { Wsrc = Wv; jrow0 = (jt - 2) * 64; }

    // stage W tile (64 j-rows x 256 c) into LDS transposed: Wlds[c][j]
    {
        const int jj = t & 63, chunk = t >> 6;
        const float* src = Wsrc + (size_t)(jrow0 + jj) * CIN + chunk * 64;
        #pragma unroll
        for (int i = 0; i < 64; ++i)
            Wlds[chunk * 64 + i][jj] = src[i];
    }
    __syncthreads();

    const int n  = nt * 64 + (t & 63);
    const int jg = t >> 6;                 // 0..3 -> 16 j's each
    const float* xb = x + (size_t)b * CIN * NN + n;

    float acc[16];
    #pragma unroll
    for (int i = 0; i < 16; ++i) acc[i] = 0.f;

    for (int c = 0; c < CIN; ++c) {
        float xv = xb[(size_t)c * NN];
        #pragma unroll
        for (int i = 0; i < 16; ++i)
            acc[i] = fmaf(xv, Wlds[c][jg * 16 + i], acc[i]);
    }

    if (jt < 2) {
        short* dst = (jt == 0 ? Qw : Kw)
                   + (size_t)b * NN * DK + (size_t)n * DK + jg * 16;
        const float s = (jt == 0) ? 0.125f : 1.0f;   // fold 1/sqrt(64) into Q
        #pragma unroll
        for (int i = 0; i < 16; ++i) dst[i] = f2bf(acc[i] * s);
    } else {
        const int o0 = (jt - 2) * 64 + jg * 16;
        short* dst = Vw + (size_t)b * DOUT * NN + n;
        #pragma unroll
        for (int i = 0; i < 16; ++i) dst[(size_t)(o0 + i) * NN] = f2bf(acc[i]);
    }
}

// ---------------------------------------------------------------------------
// Flash attention: per block 64 q-rows, 4 waves x 16 rows, KVBLK=64.
// S via mfma_f32_16x16x32_bf16 (A=Q rows, B=K^T), online softmax in D layout
// (row=(lane>>4)*4+reg, col=lane&15), P through per-wave LDS, PV MFMA,
// epilogue writes out[b][o][n] fp32.
// grid (NN/64, NB), block 256.
// NOTE: PV loop MUST be fully unrolled -- partial unroll leaves oacc[ot]
// runtime-indexed -> scratch (rule #20; round-2 showed 2.9 GB scratch writes).
// ---------------------------------------------------------------------------
__global__ __launch_bounds__(256) void attn_kernel(
    const short* __restrict__ Q, const short* __restrict__ K,
    const short* __restrict__ Vt, float* __restrict__ out)
{
    __shared__ short P_lds[4][16][64];
    const int b  = blockIdx.y;
    const int q0 = blockIdx.x * 64;
    const int w  = threadIdx.x >> 6;
    const int l  = threadIdx.x & 63;
    const int hi = l >> 4, lo = l & 15;

    const short* Qb = Q  + (size_t)b * NN * DK;
    const short* Kb = K  + (size_t)b * NN * DK;
    const short* Vb = Vt + (size_t)b * DOUT * NN;

    // Q A-fragments: lane -> row = lane&15, k = (lane>>4)*8 + j (+32 per step)
    const int qrow = q0 + w * 16 + lo;
    const short8 aq0 = *(const short8*)(Qb + (size_t)qrow * DK + hi * 8);
    const short8 aq1 = *(const short8*)(Qb + (size_t)qrow * DK + hi * 8 + 32);

    f32x4 oacc[16];
    #pragma unroll
    for (int i = 0; i < 16; ++i) oacc[i] = f32x4{0.f, 0.f, 0.f, 0.f};
    float mrun[4], lrun[4];
    #pragma unroll
    for (int r = 0; r < 4; ++r) { mrun[r] = -1e30f; lrun[r] = 0.f; }

    for (int m0 = 0; m0 < NN; m0 += 64) {
        // ---- S = Q K^T (rows: this wave's 16 q-rows; cols: 64 m) ----
        f32x4 s[4];
        #pragma unroll
        for (int mt = 0; mt < 4; ++mt) {
            const short* kr = Kb + (size_t)(m0 + mt * 16 + lo) * DK + hi * 8;
            short8 bk0 = *(const short8*)(kr);
            short8 bk1 = *(const short8*)(kr + 32);
            f32x4 acc = {0.f, 0.f, 0.f, 0.f};
            acc = __builtin_amdgcn_mfma_f32_16x16x32_bf16(aq0, bk0, acc, 0, 0, 0);
            acc = __builtin_amdgcn_mfma_f32_16x16x32_bf16(aq1, bk1, acc, 0, 0, 0);
            s[mt] = acc;
        }
        // ---- online softmax (row r lives on the 16 lanes of group hi) ----
        float rmax[4], rsum[4], alpha[4];
        #pragma unroll
        for (int r = 0; r < 4; ++r)
            rmax[r] = fmaxf(fmaxf(s[0][r], s[1][r]), fmaxf(s[2][r], s[3][r]));
        #pragma unroll
        for (int d = 1; d < 16; d <<= 1) {
            #pragma unroll
            for (int r = 0; r < 4; ++r)
                rmax[r] = fmaxf(rmax[r], __shfl_xor(rmax[r], d, 64));
        }
        #pragma unroll
        for (int r = 0; r < 4; ++r) {
            float mn = fmaxf(mrun[r], rmax[r]);
            alpha[r] = __expf(mrun[r] - mn);
            mrun[r] = mn;
            rsum[r] = 0.f;
        }
        #pragma unroll
        for (int mt = 0; mt < 4; ++mt) {
            #pragma unroll
            for (int r = 0; r < 4; ++r) {
                float p = __expf(s[mt][r] - mrun[r]);
                s[mt][r] = p;
                rsum[r] += p;
            }
        }
        #pragma unroll
        for (int d = 1; d < 16; d <<= 1) {
            #pragma unroll
            for (int r = 0; r < 4; ++r)
                rsum[r] += __shfl_xor(rsum[r], d, 64);
        }
        bool resc = false;
        #pragma unroll
        for (int r = 0; r < 4; ++r) {
            lrun[r] = lrun[r] * alpha[r] + rsum[r];
            resc |= (alpha[r] != 1.f);
        }
        if (__any(resc)) {
            #pragma unroll
            for (int i = 0; i < 16; ++i) {
                #pragma unroll
                for (int r = 0; r < 4; ++r) oacc[i][r] *= alpha[r];
            }
        }
        // ---- P -> LDS (per-wave region), re-read as A-fragment ----
        #pragma unroll
        for (int mt = 0; mt < 4; ++mt) {
            #pragma unroll
            for (int r = 0; r < 4; ++r)
                P_lds[w][hi * 4 + r][mt * 16 + lo] = f2bf(s[mt][r]);
        }
        asm volatile("s_waitcnt lgkmcnt(0)" ::: "memory");
        __builtin_amdgcn_sched_barrier(0);
        short8 pa0 = *(const short8*)(&P_lds[w][lo][hi * 8]);
        short8 pa1 = *(const short8*)(&P_lds[w][lo][hi * 8 + 32]);
        // ---- O += P V ----  (FULL unroll: all oacc indices compile-time)
        #pragma unroll
        for (int ot = 0; ot < 16; ++ot) {
            const short* vr = Vb + (size_t)(ot * 16 + lo) * NN + m0 + hi * 8;
            short8 bv0 = *(const short8*)(vr);
            short8 bv1 = *(const short8*)(vr + 32);
            oacc[ot] = __builtin_amdgcn_mfma_f32_16x16x32_bf16(pa0, bv0, oacc[ot], 0, 0, 0);
            oacc[ot] = __builtin_amdgcn_mfma_f32_16x16x32_bf16(pa1, bv1, oacc[ot], 0, 0, 0);
        }
    }
    // ---- epilogue: out[b][o][n] = oacc / l ----
    float inv[4];
    #pragma unroll
    for (int r = 0; r < 4; ++r) inv[r] = 1.f / lrun[r];
    float* ob = out + (size_t)b * DOUT * NN;
    #pragma unroll
    for (int ot = 0; ot < 16; ++ot) {
        #pragma unroll
        for (int r = 0; r < 4; ++r)
            ob[(size_t)(ot * 16 + lo) * NN + (q0 + w * 16 + hi * 4 + r)]
                = oacc[ot][r] * inv[r];
    }
}

// ---------------------------------------------------------------------------
extern "C" void kernel_launch(void* const* d_in, const int* in_sizes, int n_in,
                              void* d_out, int out_size, void* d_ws, size_t ws_size,
                              hipStream_t stream)
{
    const float* x  = (const float*)d_in[0];
    const float* Wq = (const float*)d_in[1];
    const float* Wk = (const float*)d_in[2];
    const float* Wv = (const float*)d_in[3];
    float* out = (float*)d_out;

    short* Qw = (short*)d_ws;                       // B*N*DK bf16  (4 MB)
    short* Kw = Qw + (size_t)NB * NN * DK;          // B*N*DK bf16  (4 MB)
    short* Vw = Kw + (size_t)NB * NN * DK;          // B*DOUT*N bf16 (16 MB)

    proj_kernel<<<dim3(NN / 64, 6, NB), 256, 0, stream>>>(x, Wq, Wk, Wv, Qw, Kw, Vw);
    attn_kernel<<<dim3(NN / 64, NB), 256, 0, stream>>>(Qw, Kw, Vw, out);
}

// Round 4
// 436.362 us; speedup vs baseline: 2.9758x; 1.8071x over previous
//
#include <hip/hip_runtime.h>
#include <hip/hip_bf16.h>

#define NB   8
#define CIN  256
#define NN   4096
#define DK   64
#define DOUT 256
#define NT   (NN / 64)          // 64 KV tiles
#define VTILE_BYTES (DOUT * 64 * 2)   // 32 KB per (b, tile)

typedef float f32x4 __attribute__((ext_vector_type(4)));
typedef short short8 __attribute__((ext_vector_type(8)));

__device__ __forceinline__ short f2bf(float f) {
    unsigned u = __builtin_bit_cast(unsigned, f);
    u = (u + 0x7FFFu + ((u >> 16) & 1u)) >> 16;   // RNE
    return (short)u;
}

// Swizzled byte offset of element (o, j) inside a 256x64 bf16 V tile.
// Row = 128 B = 8 x 16B chunks; chunk index XORed with (o&7)  [T2 / G4].
// proj WRITES with this map; attn's global_load_lds copies linearly; attn's
// ds_read applies the same XOR  (rule #21: both-sides-or-neither).
__device__ __forceinline__ int vtile_byte(int o, int j) {
    return o * 128 + ((((j >> 3) ^ (o & 7)) << 4)) + ((j & 7) << 1);
}

__device__ __forceinline__ void gload_lds16(const void* g, void* l) {
    __builtin_amdgcn_global_load_lds(
        (const __attribute__((address_space(1))) void*)g,
        (__attribute__((address_space(3))) void*)l, 16, 0, 0);
}

// ---------------------------------------------------------------------------
// Projection: q = x^T Wq^T / 8 (bf16, row-major NxDK)
//             k = x^T Wk^T     (bf16, row-major NxDK)
//             v -> Vw: per (b,tile) 256x64 bf16 tile, XOR-swizzled rows
// grid (NN/64, 6, NB), block 256. jt: 0=Q, 1=K, 2..5=V rows (jt-2)*64.
// ---------------------------------------------------------------------------
__global__ __launch_bounds__(256) void proj_kernel(
    const float* __restrict__ x,  const float* __restrict__ Wq,
    const float* __restrict__ Wk, const float* __restrict__ Wv,
    short* __restrict__ Qw, short* __restrict__ Kw, short* __restrict__ Vw)
{
    __shared__ float Wlds[CIN][64];
    const int tix = threadIdx.x;
    const int nt = blockIdx.x;
    const int jt = blockIdx.y;
    const int b  = blockIdx.z;

    const float* Wsrc; int jrow0;
    if (jt == 0)      { Wsrc = Wq; jrow0 = 0; }
    else if (jt == 1) { Wsrc = Wk; jrow0 = 0; }
    else              { Wsrc = Wv; jrow0 = (jt - 2) * 64; }

    // stage W tile (64 j-rows x 256 c) into LDS transposed: Wlds[c][j]
    {
        const int jj = tix & 63, chunk = tix >> 6;
        const float* src = Wsrc + (size_t)(jrow0 + jj) * CIN + chunk * 64;
        #pragma unroll
        for (int i = 0; i < 64; ++i)
            Wlds[chunk * 64 + i][jj] = src[i];
    }
    __syncthreads();

    const int jc = tix & 63;               // local n within tile
    const int n  = nt * 64 + jc;
    const int jg = tix >> 6;               // 0..3 -> 16 j's each (wave-uniform)
    const float* xb = x + (size_t)b * CIN * NN + n;

    float acc[16];
    #pragma unroll
    for (int i = 0; i < 16; ++i) acc[i] = 0.f;

    for (int c = 0; c < CIN; ++c) {
        float xv = xb[(size_t)c * NN];
        const f32x4* wrow = (const f32x4*)&Wlds[c][jg * 16];   // broadcast b128
        #pragma unroll
        for (int q = 0; q < 4; ++q) {
            f32x4 wv = wrow[q];
            #pragma unroll
            for (int r = 0; r < 4; ++r)
                acc[q * 4 + r] = fmaf(xv, wv[r], acc[q * 4 + r]);
        }
    }

    if (jt < 2) {
        short* dst = (jt == 0 ? Qw : Kw)
                   + (size_t)b * NN * DK + (size_t)n * DK + jg * 16;
        const float s = (jt == 0) ? 0.125f : 1.0f;   // fold 1/sqrt(64) into Q
        #pragma unroll
        for (int i = 0; i < 16; ++i) dst[i] = f2bf(acc[i] * s);
    } else {
        const int o0 = (jt - 2) * 64 + jg * 16;
        char* vtile = (char*)(Vw + (size_t)b * DOUT * NN) + (size_t)nt * VTILE_BYTES;
        #pragma unroll
        for (int i = 0; i < 16; ++i)
            *(short*)(vtile + vtile_byte(o0 + i, jc)) = f2bf(acc[i]);
    }
}

// ---------------------------------------------------------------------------
// Flash attention: per block 64 q-rows, 4 waves x 16 rows, KVBLK=64.
// V tile staged once per block into double-buffered LDS (global_load_lds,
// pre-swizzled source), 2-phase pipeline: K-loads -> STAGE(t+1) -> QK ->
// softmax -> P roundtrip -> PV(ds_read swz) -> vmcnt(0)+barrier.
// grid (NN/64, NB), block 256.
// NOTE: PV loop MUST be fully unrolled (rule #20: runtime-indexed oacc ->
// scratch; round-2 showed 2.9 GB scratch writes).
// ---------------------------------------------------------------------------
__global__ __launch_bounds__(256) void attn_kernel(
    const short* __restrict__ Q, const short* __restrict__ K,
    const short* __restrict__ Vt, float* __restrict__ out)
{
    __shared__ short Vlds[2][DOUT * 64];     // 2 x 32 KB
    __shared__ short P_lds[4][16][64];       // 8 KB
    const int b  = blockIdx.y;
    const int q0 = blockIdx.x * 64;
    const int w  = threadIdx.x >> 6;
    const int l  = threadIdx.x & 63;
    const int hi = l >> 4, lo = l & 15;

    const short* Qb = Q  + (size_t)b * NN * DK;
    const short* Kb = K  + (size_t)b * NN * DK;
    const char*  Vbase = (const char*)(Vt + (size_t)b * DOUT * NN);

    // Q A-fragments: lane -> row = lane&15, k = (lane>>4)*8 + j (+32 per step)
    const int qrow = q0 + w * 16 + lo;
    const short8 aq0 = *(const short8*)(Qb + (size_t)qrow * DK + hi * 8);
    const short8 aq1 = *(const short8*)(Qb + (size_t)qrow * DK + hi * 8 + 32);

    // per-lane swizzled 16B-chunk offsets for PV ds_reads (o&7 == lo&7)
    const int lo7 = lo & 7;
    const int sw0 = ((hi ^ lo7) << 4);
    const int sw1 = (((4 + hi) ^ lo7) << 4);

    f32x4 oacc[16];
    #pragma unroll
    for (int i = 0; i < 16; ++i) oacc[i] = f32x4{0.f, 0.f, 0.f, 0.f};
    float mrun[4], lrun[4];
    #pragma unroll
    for (int r = 0; r < 4; ++r) { mrun[r] = -1e30f; lrun[r] = 0.f; }

    // ---- prologue: stage tile 0 into buf 0 ----
    {
        const char* vtile = Vbase;
        #pragma unroll
        for (int kk = 0; kk < 8; ++kk) {
            const int c = kk * 4 + w;                       // 32 chunks of 1 KB
            gload_lds16(vtile + c * 1024 + l * 16,
                        (char*)&Vlds[0][0] + c * 1024);
        }
    }
    asm volatile("s_waitcnt vmcnt(0)" ::: "memory");
    __builtin_amdgcn_s_barrier();
    __builtin_amdgcn_sched_barrier(0);

    for (int t = 0; t < NT; ++t) {
        const int cur = t & 1;
        const int m0  = t * 64;

        // ---- 1. K loads for this tile (issued BEFORE stage: FIFO vmcnt) ----
        short8 bk0[4], bk1[4];
        #pragma unroll
        for (int mt = 0; mt < 4; ++mt) {
            const short* kr = Kb + (size_t)(m0 + mt * 16 + lo) * DK + hi * 8;
            bk0[mt] = *(const short8*)(kr);
            bk1[mt] = *(const short8*)(kr + 32);
        }
        __builtin_amdgcn_sched_barrier(0);

        // ---- 2. STAGE V(t+1) into the other buffer ----
        {
            const int tn = (t + 1 < NT) ? t + 1 : NT - 1;
            const char* vtile = Vbase + (size_t)tn * VTILE_BYTES;
            #pragma unroll
            for (int kk = 0; kk < 8; ++kk) {
                const int c = kk * 4 + w;
                gload_lds16(vtile + c * 1024 + l * 16,
                            (char*)&Vlds[cur ^ 1][0] + c * 1024);
            }
        }
        __builtin_amdgcn_sched_barrier(0);

        // ---- 3. S = Q K^T ----
        f32x4 s[4];
        #pragma unroll
        for (int mt = 0; mt < 4; ++mt) {
            f32x4 acc = {0.f, 0.f, 0.f, 0.f};
            acc = __builtin_amdgcn_mfma_f32_16x16x32_bf16(aq0, bk0[mt], acc, 0, 0, 0);
            acc = __builtin_amdgcn_mfma_f32_16x16x32_bf16(aq1, bk1[mt], acc, 0, 0, 0);
            s[mt] = acc;
        }
        // ---- 4. online softmax (row r lives on the 16 lanes of group hi) ----
        float rmax[4], rsum[4], alpha[4];
        #pragma unroll
        for (int r = 0; r < 4; ++r)
            rmax[r] = fmaxf(fmaxf(s[0][r], s[1][r]), fmaxf(s[2][r], s[3][r]));
        #pragma unroll
        for (int d = 1; d < 16; d <<= 1) {
            #pragma unroll
            for (int r = 0; r < 4; ++r)
                rmax[r] = fmaxf(rmax[r], __shfl_xor(rmax[r], d, 64));
        }
        #pragma unroll
        for (int r = 0; r < 4; ++r) {
            float mn = fmaxf(mrun[r], rmax[r]);
            alpha[r] = __expf(mrun[r] - mn);
            mrun[r] = mn;
            rsum[r] = 0.f;
        }
        #pragma unroll
        for (int mt = 0; mt < 4; ++mt) {
            #pragma unroll
            for (int r = 0; r < 4; ++r) {
                float p = __expf(s[mt][r] - mrun[r]);
                s[mt][r] = p;
                rsum[r] += p;
            }
        }
        #pragma unroll
        for (int d = 1; d < 16; d <<= 1) {
            #pragma unroll
            for (int r = 0; r < 4; ++r)
                rsum[r] += __shfl_xor(rsum[r], d, 64);
        }
        bool resc = false;
        #pragma unroll
        for (int r = 0; r < 4; ++r) {
            lrun[r] = lrun[r] * alpha[r] + rsum[r];
            resc |= (alpha[r] != 1.f);
        }
        if (__any(resc)) {
            #pragma unroll
            for (int i = 0; i < 16; ++i) {
                #pragma unroll
                for (int r = 0; r < 4; ++r) oacc[i][r] *= alpha[r];
            }
        }
        // ---- 5. P -> LDS (per-wave region), re-read as A-fragment ----
        #pragma unroll
        for (int mt = 0; mt < 4; ++mt) {
            #pragma unroll
            for (int r = 0; r < 4; ++r)
                P_lds[w][hi * 4 + r][mt * 16 + lo] = f2bf(s[mt][r]);
        }
        asm volatile("s_waitcnt lgkmcnt(0)" ::: "memory");
        __builtin_amdgcn_sched_barrier(0);
        short8 pa0 = *(const short8*)(&P_lds[w][lo][hi * 8]);
        short8 pa1 = *(const short8*)(&P_lds[w][lo][hi * 8 + 32]);

        // ---- 6. O += P V  (V from swizzled LDS; FULL unroll) ----
        const char* vb = (const char*)&Vlds[cur][0];
        #pragma unroll
        for (int ot = 0; ot < 16; ++ot) {
            const char* rowp = vb + (ot * 16 + lo) * 128;
            short8 bv0 = *(const short8*)(rowp + sw0);
            short8 bv1 = *(const short8*)(rowp + sw1);
            oacc[ot] = __builtin_amdgcn_mfma_f32_16x16x32_bf16(pa0, bv0, oacc[ot], 0, 0, 0);
            oacc[ot] = __builtin_amdgcn_mfma_f32_16x16x32_bf16(pa1, bv1, oacc[ot], 0, 0, 0);
        }

        // ---- 7. fence: stage(t+1) drained, all waves done reading ----
        __builtin_amdgcn_sched_barrier(0);
        asm volatile("s_waitcnt vmcnt(0)" ::: "memory");
        __builtin_amdgcn_s_barrier();
        __builtin_amdgcn_sched_barrier(0);
    }
    // ---- epilogue: out[b][o][n] = oacc / l ----
    float inv[4];
    #pragma unroll
    for (int r = 0; r < 4; ++r) inv[r] = 1.f / lrun[r];
    float* ob = out + (size_t)b * DOUT * NN;
    #pragma unroll
    for (int ot = 0; ot < 16; ++ot) {
        #pragma unroll
        for (int r = 0; r < 4; ++r)
            ob[(size_t)(ot * 16 + lo) * NN + (q0 + w * 16 + hi * 4 + r)]
                = oacc[ot][r] * inv[r];
    }
}

// ---------------------------------------------------------------------------
extern "C" void kernel_launch(void* const* d_in, const int* in_sizes, int n_in,
                              void* d_out, int out_size, void* d_ws, size_t ws_size,
                              hipStream_t stream)
{
    const float* x  = (const float*)d_in[0];
    const float* Wq = (const float*)d_in[1];
    const float* Wk = (const float*)d_in[2];
    const float* Wv = (const float*)d_in[3];
    float* out = (float*)d_out;

    short* Qw = (short*)d_ws;                       // B*N*DK bf16  (4 MB)
    short* Kw = Qw + (size_t)NB * NN * DK;          // B*N*DK bf16  (4 MB)
    short* Vw = Kw + (size_t)NB * NN * DK;          // B*DOUT*N bf16 (16 MB, tiled+swizzled)

    proj_kernel<<<dim3(NN / 64, 6, NB), 256, 0, stream>>>(x, Wq, Wk, Wv, Qw, Kw, Vw);
    attn_kernel<<<dim3(NN / 64, NB), 256, 0, stream>>>(Qw, Kw, Vw, out);
}

// Round 5
// 308.739 us; speedup vs baseline: 4.2059x; 1.4134x over previous
//
#include <hip/hip_runtime.h>
#include <hip/hip_bf16.h>

#define NB   8
#define CIN  256
#define NN   4096
#define DK   64
#define DOUT 256
#define NT   (NN / 64)          // 64 KV tiles
#define VTILE_BYTES (DOUT * 64 * 2)   // 32 KB per (b, tile)
#define JTOT 384                // 64 Q + 64 K + 256 V output channels

typedef float f32x4 __attribute__((ext_vector_type(4)));
typedef short short8 __attribute__((ext_vector_type(8)));
typedef short short4s __attribute__((ext_vector_type(4)));

__device__ __forceinline__ short f2bf(float f) {
    unsigned u = __builtin_bit_cast(unsigned, f);
    u = (u + 0x7FFFu + ((u >> 16) & 1u)) >> 16;   // RNE
    return (short)u;
}

// Swizzled byte offset of element (o, j) inside a 256x64 bf16 V tile.
// Row = 128 B = 8 x 16B chunks; chunk index XORed with (o&7)  [T2 / G4].
// proj WRITES with this map; attn's global_load_lds copies linearly; attn's
// ds_read applies the same XOR  (rule #21: both-sides-or-neither).
__device__ __forceinline__ int vtile_byte(int o, int j) {
    return o * 128 + ((((j >> 3) ^ (o & 7)) << 4)) + ((j & 7) << 1);
}

__device__ __forceinline__ void gload_lds16(const void* g, void* l) {
    __builtin_amdgcn_global_load_lds(
        (const __attribute__((address_space(1))) void*)g,
        (__attribute__((address_space(3))) void*)l, 16, 0, 0);
}

// ---------------------------------------------------------------------------
// convw: pack Wq (x 0.125*log2e, folds temperature + exp->exp2), Wk, Wv into
// one bf16 matrix Wb[384][256]. grid 384, block 256.
// ---------------------------------------------------------------------------
__global__ __launch_bounds__(256) void convw_kernel(
    const float* __restrict__ Wq, const float* __restrict__ Wk,
    const float* __restrict__ Wv, short* __restrict__ Wb)
{
    const int j = blockIdx.x;
    const int c = threadIdx.x;
    float v;
    if (j < 64)       v = Wq[j * CIN + c] * 0.18033688011f;   // 0.125*log2(e)
    else if (j < 128) v = Wk[(j - 64) * CIN + c];
    else              v = Wv[(j - 128) * CIN + c];
    Wb[(size_t)j * CIN + c] = f2bf(v);
}

// ---------------------------------------------------------------------------
// Projection via MFMA: Y[j][n] = sum_c Wb[j][c] * x[b][c][n0+n], 64 n x 384 j
// per block. x tile staged to LDS bf16, transposed [n][c] with chunk-XOR
// swizzle ^(n&7). A = Wb rows (global short8), B = x cols (LDS short8).
// D: col=lane&15=n, row=4*hi+r=j  ->  Q/K stores pack short4 (j consecutive).
// V written in the swizzled-tile format attn stages from.
// grid (NN/64, NB), block 256 (4 waves x 96 j each).
// ---------------------------------------------------------------------------
__global__ __launch_bounds__(256) void proj_kernel(
    const float* __restrict__ x, const short* __restrict__ Wb,
    short* __restrict__ Qw, short* __restrict__ Kw, short* __restrict__ Vw)
{
    __shared__ short Xt[64][256];            // 32 KB, rows swizzled
    const int t  = threadIdx.x;
    const int nt = blockIdx.x;               // n-tile (also V tile index)
    const int b  = blockIdx.y;
    const int n0 = nt * 64;
    const int w  = t >> 6;
    const int l  = t & 63;
    const int hi = l >> 4, lo = l & 15;

    // ---- stage x tile: thread (l, cg=w) loads 64 c for n = n0+l ----
    {
        const float* xs = x + (size_t)b * CIN * NN + (size_t)(w * 64) * NN + n0 + l;
        #pragma unroll
        for (int c8 = 0; c8 < 8; ++c8) {
            short8 v;
            #pragma unroll
            for (int i = 0; i < 8; ++i)
                v[i] = f2bf(xs[(size_t)(c8 * 8 + i) * NN]);
            const int c0 = w * 64 + c8 * 8;
            *(short8*)((char*)&Xt[0][0] + l * 512 + ((((c0 >> 3) ^ (l & 7)) << 4)))
                = v;
        }
    }
    __syncthreads();

    const int wj0 = w * 96;                  // wave's j range (6 tiles of 16)
    f32x4 acc[6][4];
    #pragma unroll
    for (int jt = 0; jt < 6; ++jt)
        #pragma unroll
        for (int ntl = 0; ntl < 4; ++ntl) acc[jt][ntl] = f32x4{0.f, 0.f, 0.f, 0.f};

    #pragma unroll 2
    for (int kb = 0; kb < 8; ++kb) {
        short8 aw[6], bx[4];
        #pragma unroll
        for (int jt = 0; jt < 6; ++jt)
            aw[jt] = *(const short8*)(Wb + (size_t)(wj0 + jt * 16 + lo) * CIN
                                         + kb * 32 + hi * 8);
        #pragma unroll
        for (int ntl = 0; ntl < 4; ++ntl) {
            const int n = ntl * 16 + lo;
            bx[ntl] = *(const short8*)((char*)&Xt[0][0] + n * 512
                                       + ((((kb * 4 + hi) ^ (n & 7)) << 4)));
        }
        #pragma unroll
        for (int jt = 0; jt < 6; ++jt)
            #pragma unroll
            for (int ntl = 0; ntl < 4; ++ntl)
                acc[jt][ntl] = __builtin_amdgcn_mfma_f32_16x16x32_bf16(
                    aw[jt], bx[ntl], acc[jt][ntl], 0, 0, 0);
    }

    // ---- epilogue ----
    #pragma unroll
    for (int jt = 0; jt < 6; ++jt) {
        const int jbase = wj0 + jt * 16;     // wave-uniform dest selector
        #pragma unroll
        for (int ntl = 0; ntl < 4; ++ntl) {
            const f32x4 a = acc[jt][ntl];
            const int n = ntl * 16 + lo;
            if (jbase < 64) {                // Q
                short4s pk;
                #pragma unroll
                for (int r = 0; r < 4; ++r) pk[r] = f2bf(a[r]);
                *(short4s*)(Qw + (size_t)b * NN * DK + (size_t)(n0 + n) * DK
                            + jbase + hi * 4) = pk;
            } else if (jbase < 128) {        // K
                short4s pk;
                #pragma unroll
                for (int r = 0; r < 4; ++r) pk[r] = f2bf(a[r]);
                *(short4s*)(Kw + (size_t)b * NN * DK + (size_t)(n0 + n) * DK
                            + (jbase - 64) + hi * 4) = pk;
            } else {                         // V (swizzled tile)
                const int o0 = jbase - 128 + hi * 4;
                char* vtile = (char*)(Vw + (size_t)b * DOUT * NN)
                            + (size_t)nt * VTILE_BYTES;
                #pragma unroll
                for (int r = 0; r < 4; ++r)
                    *(short*)(vtile + vtile_byte(o0 + r, n)) = f2bf(a[r]);
            }
        }
    }
}

// ---------------------------------------------------------------------------
// Flash attention: per block 64 q-rows, 4 waves x 16 rows, KVBLK=64.
// V tile staged once per block into double-buffered LDS (global_load_lds,
// pre-swizzled source), 2-phase pipeline: K-loads -> STAGE(t+1) -> QK ->
// softmax (exp2; scale folded into Q) -> P roundtrip -> PV(ds_read swz) ->
// vmcnt(0)+barrier.   grid (NN/64, NB), block 256.
// NOTE: PV loop MUST be fully unrolled (rule #20: runtime-indexed oacc ->
// scratch; round-2 showed 2.9 GB scratch writes).
// P_lds rows padded to 72 shorts: write bank-conflict 8-way -> ~free.
// ---------------------------------------------------------------------------
__global__ __launch_bounds__(256) void attn_kernel(
    const short* __restrict__ Q, const short* __restrict__ K,
    const short* __restrict__ Vt, float* __restrict__ out)
{
    __shared__ short Vlds[2][DOUT * 64];     // 2 x 32 KB
    __shared__ short P_lds[4][16][72];       // padded rows (144 B)
    const int b  = blockIdx.y;
    const int q0 = blockIdx.x * 64;
    const int w  = threadIdx.x >> 6;
    const int l  = threadIdx.x & 63;
    const int hi = l >> 4, lo = l & 15;

    const short* Qb = Q  + (size_t)b * NN * DK;
    const short* Kb = K  + (size_t)b * NN * DK;
    const char*  Vbase = (const char*)(Vt + (size_t)b * DOUT * NN);

    // Q A-fragments: lane -> row = lane&15, k = (lane>>4)*8 + j (+32 per step)
    const int qrow = q0 + w * 16 + lo;
    const short8 aq0 = *(const short8*)(Qb + (size_t)qrow * DK + hi * 8);
    const short8 aq1 = *(const short8*)(Qb + (size_t)qrow * DK + hi * 8 + 32);

    // per-lane swizzled 16B-chunk offsets for PV ds_reads (o&7 == lo&7)
    const int lo7 = lo & 7;
    const int sw0 = ((hi ^ lo7) << 4);
    const int sw1 = (((4 + hi) ^ lo7) << 4);

    f32x4 oacc[16];
    #pragma unroll
    for (int i = 0; i < 16; ++i) oacc[i] = f32x4{0.f, 0.f, 0.f, 0.f};
    float mrun[4], lrun[4];
    #pragma unroll
    for (int r = 0; r < 4; ++r) { mrun[r] = -1e30f; lrun[r] = 0.f; }

    // ---- prologue: stage tile 0 into buf 0 ----
    {
        const char* vtile = Vbase;
        #pragma unroll
        for (int kk = 0; kk < 8; ++kk) {
            const int c = kk * 4 + w;                       // 32 chunks of 1 KB
            gload_lds16(vtile + c * 1024 + l * 16,
                        (char*)&Vlds[0][0] + c * 1024);
        }
    }
    asm volatile("s_waitcnt vmcnt(0)" ::: "memory");
    __builtin_amdgcn_s_barrier();
    __builtin_amdgcn_sched_barrier(0);

    for (int t = 0; t < NT; ++t) {
        const int cur = t & 1;
        const int m0  = t * 64;

        // ---- 1. K loads for this tile (issued BEFORE stage: FIFO vmcnt) ----
        short8 bk0[4], bk1[4];
        #pragma unroll
        for (int mt = 0; mt < 4; ++mt) {
            const short* kr = Kb + (size_t)(m0 + mt * 16 + lo) * DK + hi * 8;
            bk0[mt] = *(const short8*)(kr);
            bk1[mt] = *(const short8*)(kr + 32);
        }
        __builtin_amdgcn_sched_barrier(0);

        // ---- 2. STAGE V(t+1) into the other buffer ----
        {
            const int tn = (t + 1 < NT) ? t + 1 : NT - 1;
            const char* vtile = Vbase + (size_t)tn * VTILE_BYTES;
            #pragma unroll
            for (int kk = 0; kk < 8; ++kk) {
                const int c = kk * 4 + w;
                gload_lds16(vtile + c * 1024 + l * 16,
                            (char*)&Vlds[cur ^ 1][0] + c * 1024);
            }
        }
        __builtin_amdgcn_sched_barrier(0);

        // ---- 3. S = Q K^T ----
        f32x4 s[4];
        #pragma unroll
        for (int mt = 0; mt < 4; ++mt) {
            f32x4 acc = {0.f, 0.f, 0.f, 0.f};
            acc = __builtin_amdgcn_mfma_f32_16x16x32_bf16(aq0, bk0[mt], acc, 0, 0, 0);
            acc = __builtin_amdgcn_mfma_f32_16x16x32_bf16(aq1, bk1[mt], acc, 0, 0, 0);
            s[mt] = acc;
        }
        // ---- 4. online softmax, base-2 (row r on the 16 lanes of group hi) --
        float rmax[4], rsum[4], alpha[4];
        #pragma unroll
        for (int r = 0; r < 4; ++r)
            rmax[r] = fmaxf(fmaxf(s[0][r], s[1][r]), fmaxf(s[2][r], s[3][r]));
        #pragma unroll
        for (int d = 1; d < 16; d <<= 1) {
            #pragma unroll
            for (int r = 0; r < 4; ++r)
                rmax[r] = fmaxf(rmax[r], __shfl_xor(rmax[r], d, 64));
        }
        #pragma unroll
        for (int r = 0; r < 4; ++r) {
            float mn = fmaxf(mrun[r], rmax[r]);
            alpha[r] = __builtin_amdgcn_exp2f(mrun[r] - mn);
            mrun[r] = mn;
            rsum[r] = 0.f;
        }
        #pragma unroll
        for (int mt = 0; mt < 4; ++mt) {
            #pragma unroll
            for (int r = 0; r < 4; ++r) {
                float p = __builtin_amdgcn_exp2f(s[mt][r] - mrun[r]);
                s[mt][r] = p;
                rsum[r] += p;
            }
        }
        #pragma unroll
        for (int d = 1; d < 16; d <<= 1) {
            #pragma unroll
            for (int r = 0; r < 4; ++r)
                rsum[r] += __shfl_xor(rsum[r], d, 64);
        }
        bool resc = false;
        #pragma unroll
        for (int r = 0; r < 4; ++r) {
            lrun[r] = lrun[r] * alpha[r] + rsum[r];
            resc |= (alpha[r] != 1.f);
        }
        if (__any(resc)) {
            #pragma unroll
            for (int i = 0; i < 16; ++i) {
                #pragma unroll
                for (int r = 0; r < 4; ++r) oacc[i][r] *= alpha[r];
            }
        }
        // ---- 5. P -> LDS (per-wave region), re-read as A-fragment ----
        #pragma unroll
        for (int mt = 0; mt < 4; ++mt) {
            #pragma unroll
            for (int r = 0; r < 4; ++r)
                P_lds[w][hi * 4 + r][mt * 16 + lo] = f2bf(s[mt][r]);
        }
        asm volatile("s_waitcnt lgkmcnt(0)" ::: "memory");
        __builtin_amdgcn_sched_barrier(0);
        short8 pa0 = *(const short8*)(&P_lds[w][lo][hi * 8]);
        short8 pa1 = *(const short8*)(&P_lds[w][lo][hi * 8 + 32]);

        // ---- 6. O += P V  (V from swizzled LDS; FULL unroll) ----
        const char* vb = (const char*)&Vlds[cur][0];
        #pragma unroll
        for (int ot = 0; ot < 16; ++ot) {
            const char* rowp = vb + (ot * 16 + lo) * 128;
            short8 bv0 = *(const short8*)(rowp + sw0);
            short8 bv1 = *(const short8*)(rowp + sw1);
            oacc[ot] = __builtin_amdgcn_mfma_f32_16x16x32_bf16(pa0, bv0, oacc[ot], 0, 0, 0);
            oacc[ot] = __builtin_amdgcn_mfma_f32_16x16x32_bf16(pa1, bv1, oacc[ot], 0, 0, 0);
        }

        // ---- 7. fence: stage(t+1) drained, all waves done reading ----
        __builtin_amdgcn_sched_barrier(0);
        asm volatile("s_waitcnt vmcnt(0)" ::: "memory");
        __builtin_amdgcn_s_barrier();
        __builtin_amdgcn_sched_barrier(0);
    }
    // ---- epilogue: out[b][o][n] = oacc / l ----
    float inv[4];
    #pragma unroll
    for (int r = 0; r < 4; ++r) inv[r] = 1.f / lrun[r];
    float* ob = out + (size_t)b * DOUT * NN;
    #pragma unroll
    for (int ot = 0; ot < 16; ++ot) {
        #pragma unroll
        for (int r = 0; r < 4; ++r)
            ob[(size_t)(ot * 16 + lo) * NN + (q0 + w * 16 + hi * 4 + r)]
                = oacc[ot][r] * inv[r];
    }
}

// ---------------------------------------------------------------------------
extern "C" void kernel_launch(void* const* d_in, const int* in_sizes, int n_in,
                              void* d_out, int out_size, void* d_ws, size_t ws_size,
                              hipStream_t stream)
{
    const float* x  = (const float*)d_in[0];
    const float* Wq = (const float*)d_in[1];
    const float* Wk = (const float*)d_in[2];
    const float* Wv = (const float*)d_in[3];
    float* out = (float*)d_out;

    short* Qw = (short*)d_ws;                       // B*N*DK bf16  (4 MB)
    short* Kw = Qw + (size_t)NB * NN * DK;          // B*N*DK bf16  (4 MB)
    short* Vw = Kw + (size_t)NB * NN * DK;          // B*DOUT*N bf16 (16 MB, tiled+swizzled)
    // Wb (192 KB bf16) lives at the START of d_out: convw writes it, proj
    // reads it, attn later overwrites all of d_out (stream-ordered -> safe,
    // and avoids exceeding the 24 MB of d_ws already in use).
    short* Wb = (short*)d_out;

    convw_kernel<<<dim3(JTOT), 256, 0, stream>>>(Wq, Wk, Wv, Wb);
    proj_kernel<<<dim3(NN / 64, NB), 256, 0, stream>>>(x, Wb, Qw, Kw, Vw);
    attn_kernel<<<dim3(NN / 64, NB), 256, 0, stream>>>(Qw, Kw, Vw, out);
}